// Round 12
// baseline (151.032 us; speedup 1.0000x reference)
//
#include <hip/hip_runtime.h>
#include <hip/hip_bf16.h>

#define T_TOK 2048
#define H_DIM 1024
#define I_DIM 768
#define NEXP  8
#define WPE   6291456   // weight elems per array (E*I*H)

typedef short bf16x8  __attribute__((ext_vector_type(8)));
typedef short short4v __attribute__((ext_vector_type(4)));
typedef float f32x4   __attribute__((ext_vector_type(4)));

__device__ __forceinline__ short f2bf(float f) {
  __bf16 b = (__bf16)f;
  return __builtin_bit_cast(short, b);
}
__device__ __forceinline__ void gload16(const void* g, void* l) {
  __builtin_amdgcn_global_load_lds(
      (const __attribute__((address_space(1))) void*)g,
      (__attribute__((address_space(3))) void*)l, 16, 0, 0);
}
__device__ __forceinline__ int padcnt(int c) { return (c + 127) & ~127; }
__device__ __forceinline__ int ebase(const int* __restrict__ cnts, int e) {
  int b = 0;
#pragma unroll
  for (int i = 0; i < NEXP; ++i)
    if (i < e) b += padcnt(cnts[i]);
  return b;
}

// ws layout: 0: counts[8] | 256: lists[8*2048 ints] | 131072: wbf (gate++up++down bf16)
// 37879808: xc (5120*1024 bf16) | 48365568: h (5120*768 bf16)

// ---- kernel A: routing compaction (8 blocks x 512)
__global__ __launch_bounds__(512) void compact_k(const float* __restrict__ routw,
                                                 int* __restrict__ wsI) {
  __shared__ int sc[8];
  int e = blockIdx.x, lane = threadIdx.x & 63, w = threadIdx.x >> 6;
  unsigned long long mk[4];
  int cnt = 0;
#pragma unroll
  for (int c = 0; c < 4; ++c) {
    int tk = w * 256 + c * 64 + lane;
    float v = routw[(size_t)tk * NEXP + e];
    mk[c] = __ballot(v > 0.f);
    cnt += __popcll(mk[c]);
  }
  if (lane == 0) sc[w] = cnt;
  __syncthreads();
  int run = 0;
#pragma unroll
  for (int j = 0; j < 8; ++j)
    if (j < w) run += sc[j];
#pragma unroll
  for (int c = 0; c < 4; ++c) {
    int tk = w * 256 + c * 64 + lane;
    if ((mk[c] >> lane) & 1ull) {
      int pos = __popcll(mk[c] & ((1ull << lane) - 1));
      wsI[64 + e * T_TOK + run + pos] = tk;
    }
    run += __popcll(mk[c]);
  }
  if (w == 7 && lane == 0) wsI[e] = run;
}

// ---- kernel B: ALL bandwidth work.
// blocks [0,4096): xgather | [4096,8704): wconv g/u/d | [8704,9216): zerofill out
__global__ __launch_bounds__(256) void pre_k(const float* __restrict__ x,
                                             const float* __restrict__ gw,
                                             const float* __restrict__ uw,
                                             const float* __restrict__ dw,
                                             const int* __restrict__ wsI,
                                             unsigned short* __restrict__ xc,
                                             unsigned short* __restrict__ wbf,
                                             float* __restrict__ out) {
  int bid = blockIdx.x, tid = threadIdx.x;
  if (bid < 4096) {            // xgather: 4 rows/block, zero-pad to pad128
    int e = bid >> 9, rb = bid & 511;
    int cnt = wsI[e];
    int pad = padcnt(cnt);
    int r = rb * 4 + (tid >> 6);
    if (r >= pad) return;
    int base = ebase(wsI, e);
    int col = (tid & 63) * 16;
    unsigned short* dst = xc + (size_t)(base + r) * H_DIM + col;
    if (r < cnt) {
      int tok = wsI[64 + e * T_TOK + r];
      const float* sr = x + (size_t)tok * H_DIM + col;
#pragma unroll
      for (int j = 0; j < 4; ++j) {
        float4 v = *(const float4*)(sr + j * 4);
        short4v b = {f2bf(v.x), f2bf(v.y), f2bf(v.z), f2bf(v.w)};
        *(short4v*)(dst + j * 4) = b;
      }
    } else {
#pragma unroll
      for (int j = 0; j < 4; ++j) {
        short4v z = {0, 0, 0, 0};
        *(short4v*)(dst + j * 4) = z;
      }
    }
  } else if (bid < 8704) {     // wconv: gate ++ up ++ down fp32->bf16, exact cover
    size_t off = ((size_t)(bid - 4096) * 256 + tid) * 16;
    int a = (int)(off / (size_t)WPE);
    size_t rem = off - (size_t)a * WPE;
    const float* s = ((a == 0) ? gw : (a == 1) ? uw : dw) + rem;
    unsigned short* o = wbf + (size_t)a * WPE + rem;
#pragma unroll
    for (int j = 0; j < 4; ++j) {
      float4 v = *(const float4*)(s + j * 4);
      short4v b = {f2bf(v.x), f2bf(v.y), f2bf(v.z), f2bf(v.w)};
      *(short4v*)(o + j * 4) = b;
    }
  } else {                     // zerofill out
    size_t off = ((size_t)(bid - 8704) * 256 + tid) * 16;
    f32x4 z = {0.f, 0.f, 0.f, 0.f};
#pragma unroll
    for (int j = 0; j < 4; ++j) *(f32x4*)(out + off + j * 4) = z;
  }
}

// ---- kernel C: gemm1 as BARRIER-FREE register GEMM.
// h = silu(Xc Wg^T)*(Xc Wu^T). Each wave: 64x64 output, A/B direct global->VGPR,
// double-buffered K32 steps, 16 MFMA/step, NO LDS staging, NO barriers in K-loop.
// Block = 4 waves: w0,w1 = gate cols gc0+64w; w2,w3 = up (same cols). SiLU pairing
// via one epilogue LDS exchange. grid = 8e * 32mt * 6ng = 1536, 256 thr.
__global__ __launch_bounds__(256, 3) void gemm1_k(
    const unsigned short* __restrict__ xc, const unsigned short* __restrict__ wbf,
    const int* __restrict__ wsI, unsigned short* __restrict__ h) {
  int e = blockIdx.x & 7, rr = blockIdx.x >> 3;
  int mt = rr & 31, ng = rr >> 5;          // mt 0..31 (64-row tiles), ng 0..5 (128 G-cols)
  int cnt = wsI[e];
  int m0 = mt * 64;
  if (m0 >= cnt) return;
  int base = ebase(wsI, e);

  __shared__ float uex[2][64][65];         // U exchange, pad 65 (bank-clean)

  int tid = threadIdx.x, lane = tid & 63, w = tid >> 6;   // 4 waves
  int fr = lane & 15, fg = lane >> 4;
  int isU = w >> 1;                        // 0: gate-wave, 1: up-wave
  int wp = w & 1;                          // pair id
  int n0 = ng * 128 + 64 * wp;             // output col base (in I_DIM)

  const unsigned short* wsrc = wbf + (size_t)isU * WPE;
  const unsigned short* pa[4];
  const unsigned short* pb[4];
#pragma unroll
  for (int m = 0; m < 4; ++m)
    pa[m] = xc + (size_t)(base + m0 + m * 16 + fr) * H_DIM + fg * 8;
#pragma unroll
  for (int n = 0; n < 4; ++n)
    pb[n] = wsrc + (size_t)(e * I_DIM + n0 + n * 16 + fr) * H_DIM + fg * 8;

  f32x4 acc[4][4] = {};
  bf16x8 a0[4], b0[4], a1[4], b1[4];       // named double buffers (static reg indexing)

#define LD1(A, B, ks)                                                \
  do {                                                               \
    _Pragma("unroll") for (int m = 0; m < 4; ++m)                    \
      A[m] = *(const bf16x8*)(pa[m] + (ks) * 32);                    \
    _Pragma("unroll") for (int n = 0; n < 4; ++n)                    \
      B[n] = *(const bf16x8*)(pb[n] + (ks) * 32);                    \
  } while (0)
#define MM1(A, B)                                                    \
  do {                                                               \
    _Pragma("unroll") for (int m = 0; m < 4; ++m)                    \
      _Pragma("unroll") for (int n = 0; n < 4; ++n)                  \
        acc[m][n] = __builtin_amdgcn_mfma_f32_16x16x32_bf16(A[m], B[n], acc[m][n], 0, 0, 0); \
  } while (0)

  LD1(a0, b0, 0);
  LD1(a1, b1, 1);
#pragma unroll
  for (int i = 0; i < 16; ++i) {           // 32 K-steps, 2 per iter
    MM1(a0, b0);
    if (i < 15) LD1(a0, b0, 2 * i + 2);
    MM1(a1, b1);
    if (i < 15) LD1(a1, b1, 2 * i + 3);
  }
#undef LD1
#undef MM1

  // epilogue: U-waves export to LDS, G-waves combine + write h
  if (isU) {
#pragma unroll
    for (int m = 0; m < 4; ++m)
#pragma unroll
      for (int n = 0; n < 4; ++n)
#pragma unroll
        for (int j = 0; j < 4; ++j)
          uex[wp][m * 16 + fg * 4 + j][n * 16 + fr] = acc[m][n][j];
  }
  __syncthreads();
  if (!isU) {
#pragma unroll
    for (int m = 0; m < 4; ++m)
#pragma unroll
      for (int j = 0; j < 4; ++j) {
        int row = m * 16 + fg * 4 + j;     // C/D: col=lane&15, row=(lane>>4)*4+reg
        size_t hb = (size_t)(base + m0 + row) * I_DIM + n0;
#pragma unroll
        for (int n = 0; n < 4; ++n) {
          float g = acc[m][n][j];
          float u = uex[wp][row][n * 16 + fr];
          h[hb + n * 16 + fr] = (unsigned short)f2bf(g * u / (1.f + __expf(-g)));
        }
      }
  }
}

// ---- shared pipeline macro for gemm2 (depth-5 ring, counted vmcnt)
#define WB(v)                                              \
  do {                                                     \
    asm volatile("s_waitcnt vmcnt(" #v ")" ::: "memory");  \
    __builtin_amdgcn_s_barrier();                          \
    __builtin_amdgcn_sched_barrier(0);                     \
  } while (0)

// ---- kernel D: gemm2: out[t] += rw * (h_e down^T). Tile M128 x N256, 24 halves,
// depth-5 half-ring, vmcnt(6). grid = 8e * 16mt * 4nt = 512. (unchanged from r11)
__global__ __launch_bounds__(512, 2) void gemm2_k(
    const unsigned short* __restrict__ h, const unsigned short* __restrict__ wbf,
    const int* __restrict__ wsI, const float* __restrict__ routw,
    float* __restrict__ out) {
  int e = blockIdx.x & 7, rr = blockIdx.x >> 3;
  int mt = rr & 15, nt = rr >> 4;       // nt 0..3
  int cnt = wsI[e];
  int m0 = mt * 128;
  if (m0 >= cnt) return;
  int base = ebase(wsI, e);
  int n0 = nt * 256;
  const unsigned short* down_bf = wbf + 2 * (size_t)WPE;

  __shared__ unsigned short ls[5][12288];   // A[128][32]@0, B[256][32]@4096

  int tid = threadIdx.x, lane = tid & 63, w = tid >> 6;
  int wm = w >> 2, wn = w & 3;
  int fr = lane & 15, fg = lane >> 4;
  int srow = lane >> 2;
  int scol = (((lane & 3) ^ (srow & 3) ^ ((srow >> 2) & 1))) * 8;

  const unsigned short* srcA  = h + (size_t)(base + m0 + 16 * w + srow) * I_DIM + scol;
  const unsigned short* srcB1 = down_bf + (size_t)(e * H_DIM + n0 + 16 * w + srow) * I_DIM + scol;
  const unsigned short* srcB2 = down_bf + (size_t)(e * H_DIM + n0 + 16 * (w + 8) + srow) * I_DIM + scol;

  int sl = ((fg ^ (fr & 3) ^ ((fr >> 2) & 1)) << 3);
  int roA[4], roB[4];
#pragma unroll
  for (int m = 0; m < 4; ++m) roA[m] = (wm * 64 + m * 16 + fr) * 32 + sl;
#pragma unroll
  for (int n = 0; n < 4; ++n) roB[n] = 4096 + (wn * 64 + n * 16 + fr) * 32 + sl;

  bf16x8 af[2][4], bv[2][4];
  f32x4 acc[4][4] = {};

#define STG2(hh)                                                     \
  do {                                                               \
    unsigned short* lb = &ls[(hh) % 5][0];                           \
    gload16(srcA + (hh) * 32, lb + w * 512);                         \
    gload16(srcB1 + (hh) * 32, lb + 4096 + w * 512);                 \
    gload16(srcB2 + (hh) * 32, lb + 4096 + (w + 8) * 512);           \
  } while (0)
#define LDF2(st, hh)                                                 \
  do {                                                               \
    const unsigned short* lb = &ls[(hh) % 5][0];                     \
    _Pragma("unroll") for (int m = 0; m < 4; ++m) af[st][m] = *(const bf16x8*)(lb + roA[m]); \
    _Pragma("unroll") for (int n = 0; n < 4; ++n) bv[st][n] = *(const bf16x8*)(lb + roB[n]); \
  } while (0)
#define MM2(st)                                                      \
  do {                                                               \
    __builtin_amdgcn_s_setprio(1);                                   \
    _Pragma("unroll") for (int m = 0; m < 4; ++m)                    \
      _Pragma("unroll") for (int n = 0; n < 4; ++n)                  \
        acc[m][n] = __builtin_amdgcn_mfma_f32_16x16x32_bf16(af[st][m], bv[st][n], acc[m][n], 0, 0, 0); \
    __builtin_amdgcn_s_setprio(0);                                   \
  } while (0)

  STG2(0); STG2(1); STG2(2); STG2(3);
  WB(6);
  LDF2(0, 0);
#pragma unroll
  for (int i = 0; i < 24; ++i) {
    if (i + 4 < 24) STG2(i + 4);
    if (i + 1 < 24) LDF2((i + 1) & 1, i + 1);
    MM2(i & 1);
    if (i <= 19)      WB(6);
    else if (i == 20) WB(3);
    else if (i == 21) WB(0);
  }
#undef STG2
#undef LDF2
#undef MM2

#pragma unroll
  for (int m = 0; m < 4; ++m)
#pragma unroll
    for (int j = 0; j < 4; ++j) {
      int row = wm * 64 + m * 16 + fg * 4 + j;
      int grow = m0 + row;
      if (grow < cnt) {
        int tk = wsI[64 + e * T_TOK + grow];
        float rw = routw[(size_t)tk * NEXP + e];
        float* orow = out + (size_t)tk * H_DIM + n0 + wn * 64;
#pragma unroll
        for (int n = 0; n < 4; ++n)
          atomicAdd(orow + n * 16 + fr, acc[m][n][j] * rw);
      }
    }
}

extern "C" void kernel_launch(void* const* d_in, const int* in_sizes, int n_in,
                              void* d_out, int out_size, void* d_ws, size_t ws_size,
                              hipStream_t stream) {
  const float* x      = (const float*)d_in[0];
  const float* gate_w = (const float*)d_in[1];
  const float* up_w   = (const float*)d_in[2];
  const float* down_w = (const float*)d_in[3];
  const float* routw  = (const float*)d_in[4];
  float* out = (float*)d_out;
  int* wsI = (int*)d_ws;

  unsigned short* wbf = (unsigned short*)((char*)d_ws + 131072);
  unsigned short* xc  = (unsigned short*)((char*)d_ws + 37879808);
  unsigned short* h   = (unsigned short*)((char*)d_ws + 48365568);

  compact_k<<<8, 512, 0, stream>>>(routw, wsI);
  pre_k<<<9216, 256, 0, stream>>>(x, gate_w, up_w, down_w, wsI, xc, wbf, out);
  gemm1_k<<<1536, 256, 0, stream>>>(xc, wbf, wsI, h);
  gemm2_k<<<512, 512, 0, stream>>>(h, wbf, wsI, routw, out);
}

// Round 13
// 91.601 us; speedup vs baseline: 1.6488x; 1.6488x over previous
//
#include <hip/hip_runtime.h>
#include <hip/hip_bf16.h>

#define T_TOK 2048
#define H_DIM 1024
#define I_DIM 768
#define NEXP  8
#define XSTR  1056   // padded row stride in shorts (2112B = 33 x 64B): non-pow2, channel-spread
#define WSTR  1056

typedef short bf16x8  __attribute__((ext_vector_type(8)));
typedef short short4v __attribute__((ext_vector_type(4)));
typedef float f32x4   __attribute__((ext_vector_type(4)));

__device__ __forceinline__ short f2bf(float f) {
  __bf16 b = (__bf16)f;
  return __builtin_bit_cast(short, b);
}
__device__ __forceinline__ void gload16(const void* g, void* l) {
  __builtin_amdgcn_global_load_lds(
      (const __attribute__((address_space(1))) void*)g,
      (__attribute__((address_space(3))) void*)l, 16, 0, 0);
}
__device__ __forceinline__ int padcnt(int c) { return (c + 127) & ~127; }
__device__ __forceinline__ int ebase(const int* __restrict__ cnts, int e) {
  int b = 0;
#pragma unroll
  for (int i = 0; i < NEXP; ++i)
    if (i < e) b += padcnt(cnts[i]);
  return b;
}

// ws layout (bytes):
// 0: counts[8] | 256: lists[8*2048] | 131072: x_bf [2049][1056] (row 2048 = zeros)
// 4458560: gate_bf [6144][1056] | 17434688: up_bf [6144][1056]
// 30410816: down_bf [8192][768] | 42993728: h [5120][768]  (ends 50858048 < 56.2MB proven)

// ---- kernel A: routing compaction; pad entries -> token 2048 (zero row)
__global__ __launch_bounds__(512) void compact_k(const float* __restrict__ routw,
                                                 int* __restrict__ wsI) {
  __shared__ int sc[8];
  int e = blockIdx.x, tid = threadIdx.x, lane = tid & 63, w = tid >> 6;
  unsigned long long mk[4];
  int cnt = 0;
#pragma unroll
  for (int c = 0; c < 4; ++c) {
    int tk = w * 256 + c * 64 + lane;
    float v = routw[(size_t)tk * NEXP + e];
    mk[c] = __ballot(v > 0.f);
    cnt += __popcll(mk[c]);
  }
  if (lane == 0) sc[w] = cnt;
  __syncthreads();
  int run = 0, tot = 0;
#pragma unroll
  for (int j = 0; j < 8; ++j) {
    if (j < w) run += sc[j];
    tot += sc[j];
  }
#pragma unroll
  for (int c = 0; c < 4; ++c) {
    int tk = w * 256 + c * 64 + lane;
    if ((mk[c] >> lane) & 1ull) {
      int pos = __popcll(mk[c] & ((1ull << lane) - 1));
      wsI[64 + e * T_TOK + run + pos] = tk;
    }
    run += __popcll(mk[c]);
  }
  if (w == 7 && lane == 0) wsI[e] = tot;
  int pad = padcnt(tot);
  for (int r = tot + tid; r < pad; r += 512) wsI[64 + e * T_TOK + r] = T_TOK;  // zero row
}

// ---- kernel B: all conversions + zerofill (no gather pass needed anymore)
// [0,520): x conv rows 0..2048 (row 2048 zeroed) | [520,2056): gate | [2056,3592): up
// [3592,5128): down | [5128,5640): zerofill out
__global__ __launch_bounds__(256) void pre_k(const float* __restrict__ x,
                                             const float* __restrict__ gw,
                                             const float* __restrict__ uw,
                                             const float* __restrict__ dw,
                                             unsigned short* __restrict__ x_bf,
                                             unsigned short* __restrict__ gbf,
                                             unsigned short* __restrict__ ubf,
                                             unsigned short* __restrict__ dbf,
                                             float* __restrict__ out) {
  int bid = blockIdx.x, tid = threadIdx.x;
  int col = (tid & 63) * 16;
  if (bid < 520) {             // x fp32->bf16 into padded rows; row 2048 = zeros
    int r = bid * 4 + (tid >> 6);
    if (r > 2048) return;
    unsigned short* dst = x_bf + (size_t)r * XSTR + col;
    if (r < 2048) {
      const float* sr = x + (size_t)r * H_DIM + col;
#pragma unroll
      for (int j = 0; j < 4; ++j) {
        float4 v = *(const float4*)(sr + j * 4);
        short4v b = {f2bf(v.x), f2bf(v.y), f2bf(v.z), f2bf(v.w)};
        *(short4v*)(dst + j * 4) = b;
      }
    } else {
#pragma unroll
      for (int j = 0; j < 4; ++j) {
        short4v z = {0, 0, 0, 0};
        *(short4v*)(dst + j * 4) = z;
      }
    }
  } else if (bid < 3592) {     // gate/up fp32->bf16 into padded rows (6144 rows each)
    int a = (bid < 2056) ? 0 : 1;
    int r = (bid - (a ? 2056 : 520)) * 4 + (tid >> 6);
    const float* s = (a ? uw : gw) + (size_t)r * H_DIM + col;
    unsigned short* dst = (a ? ubf : gbf) + (size_t)r * WSTR + col;
#pragma unroll
    for (int j = 0; j < 4; ++j) {
      float4 v = *(const float4*)(s + j * 4);
      short4v b = {f2bf(v.x), f2bf(v.y), f2bf(v.z), f2bf(v.w)};
      *(short4v*)(dst + j * 4) = b;
    }
  } else if (bid < 5128) {     // down fp32->bf16, contiguous (768 stride already non-pow2)
    size_t off = ((size_t)(bid - 3592) * 256 + tid) * 16;
    const float* s = dw + off;
    unsigned short* o = dbf + off;
#pragma unroll
    for (int j = 0; j < 4; ++j) {
      float4 v = *(const float4*)(s + j * 4);
      short4v b = {f2bf(v.x), f2bf(v.y), f2bf(v.z), f2bf(v.w)};
      *(short4v*)(o + j * 4) = b;
    }
  } else {                     // zerofill out
    size_t off = ((size_t)(bid - 5128) * 256 + tid) * 16;
    f32x4 z = {0.f, 0.f, 0.f, 0.f};
#pragma unroll
    for (int j = 0; j < 4; ++j) *(f32x4*)(out + off + j * 4) = z;
  }
}

// ---- shared pipeline macro: counted-vmcnt barrier (depth-5 ring, 3 loads/half/wave)
#define WB(v)                                              \
  do {                                                     \
    asm volatile("s_waitcnt vmcnt(" #v ")" ::: "memory");  \
    __builtin_amdgcn_s_barrier();                          \
    __builtin_amdgcn_sched_barrier(0);                     \
  } while (0)

// ---- kernel C: gemm1: h = silu(X Wg^T)*(X Wu^T). r11 structure; A gathered per-lane
// from padded x_bf (random token rows -> channel-spread), B from padded gate/up.
// Tile M128 x (G128++U128), 8 waves, depth-5 half-ring, vmcnt(6). grid 768.
__global__ __launch_bounds__(512, 2) void gemm1_k(
    const unsigned short* __restrict__ x_bf, const unsigned short* __restrict__ gbf,
    const unsigned short* __restrict__ ubf, const int* __restrict__ wsI,
    unsigned short* __restrict__ h) {
  int e = blockIdx.x & 7, rr = blockIdx.x >> 3;
  int mt = rr & 15, nt = rr >> 4;       // nt 0..5
  int cnt = wsI[e];
  int m0 = mt * 128;
  if (m0 >= cnt) return;
  int base = ebase(wsI, e);
  int n0 = nt * 128;

  __shared__ unsigned short ls[5][12288];   // per half: A[128][32]@0, B[256][32]@4096

  int tid = threadIdx.x, lane = tid & 63, w = tid >> 6;
  int wm = w >> 2, wn = w & 3;
  int fr = lane & 15, fg = lane >> 4;
  int srow = lane >> 2;
  int scol = (((lane & 3) ^ (srow & 3) ^ ((srow >> 2) & 1))) * 8;

  int tokA = wsI[64 + e * T_TOK + m0 + 16 * w + srow];  // per-lane gather; pad rows -> 2048 (zeros)
  const unsigned short* srcA = x_bf + (size_t)tokA * XSTR + scol;
  const unsigned short* srcG = gbf + (size_t)(e * I_DIM + n0 + 16 * w + srow) * WSTR + scol;
  const unsigned short* srcU = ubf + (size_t)(e * I_DIM + n0 + 16 * w + srow) * WSTR + scol;

  int sl = ((fg ^ (fr & 3) ^ ((fr >> 2) & 1)) << 3);
  int roA[4], roB[4];
#pragma unroll
  for (int m = 0; m < 4; ++m) roA[m] = (wm * 64 + m * 16 + fr) * 32 + sl;
#pragma unroll
  for (int n = 0; n < 4; ++n) {
    int r2 = (n < 2) ? (wn * 32 + n * 16 + fr) : (128 + wn * 32 + (n - 2) * 16 + fr);
    roB[n] = 4096 + r2 * 32 + sl;
  }

  bf16x8 af[2][4], bv[2][4];
  f32x4 acc[4][4] = {};   // [m][jn]: jn 0,1 = G cols; 2,3 = U cols

#define STG1(hh)                                                     \
  do {                                                               \
    unsigned short* lb = &ls[(hh) % 5][0];                           \
    gload16(srcA + (hh) * 32, lb + w * 512);                         \
    gload16(srcG + (hh) * 32, lb + 4096 + w * 512);                  \
    gload16(srcU + (hh) * 32, lb + 4096 + (w + 8) * 512);            \
  } while (0)
#define LDF1(st, hh)                                                 \
  do {                                                               \
    const unsigned short* lb = &ls[(hh) % 5][0];                     \
    _Pragma("unroll") for (int m = 0; m < 4; ++m) af[st][m] = *(const bf16x8*)(lb + roA[m]); \
    _Pragma("unroll") for (int n = 0; n < 4; ++n) bv[st][n] = *(const bf16x8*)(lb + roB[n]); \
  } while (0)
#define MM1(st)                                                      \
  do {                                                               \
    __builtin_amdgcn_s_setprio(1);                                   \
    _Pragma("unroll") for (int m = 0; m < 4; ++m)                    \
      _Pragma("unroll") for (int n = 0; n < 4; ++n)                  \
        acc[m][n] = __builtin_amdgcn_mfma_f32_16x16x32_bf16(af[st][m], bv[st][n], acc[m][n], 0, 0, 0); \
    __builtin_amdgcn_s_setprio(0);                                   \
  } while (0)

  STG1(0); STG1(1); STG1(2); STG1(3);
  WB(6);                       // halves 0,1 landed; 2,3 in flight
  LDF1(0, 0);
#pragma unroll
  for (int i = 0; i < 32; ++i) {
    if (i + 4 < 32) STG1(i + 4);
    if (i + 1 < 32) LDF1((i + 1) & 1, i + 1);
    MM1(i & 1);
    if (i <= 27)      WB(6);
    else if (i == 28) WB(3);
    else if (i == 29) WB(0);
  }
#undef STG1
#undef LDF1
#undef MM1

#pragma unroll
  for (int m = 0; m < 4; ++m)
#pragma unroll
    for (int j = 0; j < 4; ++j) {
      int row = wm * 64 + m * 16 + fg * 4 + j;   // C/D: col=lane&15, row=(lane>>4)*4+reg
      size_t rb2 = (size_t)(base + m0 + row) * I_DIM + n0;
#pragma unroll
      for (int jn = 0; jn < 2; ++jn) {
        float g = acc[m][jn][j];
        float u = acc[m][jn + 2][j];
        h[rb2 + wn * 32 + jn * 16 + fr] = (unsigned short)f2bf(g * u / (1.f + __expf(-g)));
      }
    }
}

// ---- kernel D: gemm2: out[t] += rw * (h_e down^T). Unchanged r11 structure. grid 512.
__global__ __launch_bounds__(512, 2) void gemm2_k(
    const unsigned short* __restrict__ h, const unsigned short* __restrict__ dbf,
    const int* __restrict__ wsI, const float* __restrict__ routw,
    float* __restrict__ out) {
  int e = blockIdx.x & 7, rr = blockIdx.x >> 3;
  int mt = rr & 15, nt = rr >> 4;       // nt 0..3
  int cnt = wsI[e];
  int m0 = mt * 128;
  if (m0 >= cnt) return;
  int base = ebase(wsI, e);
  int n0 = nt * 256;

  __shared__ unsigned short ls[5][12288];   // A[128][32]@0, B[256][32]@4096

  int tid = threadIdx.x, lane = tid & 63, w = tid >> 6;
  int wm = w >> 2, wn = w & 3;
  int fr = lane & 15, fg = lane >> 4;
  int srow = lane >> 2;
  int scol = (((lane & 3) ^ (srow & 3) ^ ((srow >> 2) & 1))) * 8;

  const unsigned short* srcA  = h + (size_t)(base + m0 + 16 * w + srow) * I_DIM + scol;
  const unsigned short* srcB1 = dbf + (size_t)(e * H_DIM + n0 + 16 * w + srow) * I_DIM + scol;
  const unsigned short* srcB2 = dbf + (size_t)(e * H_DIM + n0 + 16 * (w + 8) + srow) * I_DIM + scol;

  int sl = ((fg ^ (fr & 3) ^ ((fr >> 2) & 1)) << 3);
  int roA[4], roB[4];
#pragma unroll
  for (int m = 0; m < 4; ++m) roA[m] = (wm * 64 + m * 16 + fr) * 32 + sl;
#pragma unroll
  for (int n = 0; n < 4; ++n) roB[n] = 4096 + (wn * 64 + n * 16 + fr) * 32 + sl;

  bf16x8 af[2][4], bv[2][4];
  f32x4 acc[4][4] = {};

#define STG2(hh)                                                     \
  do {                                                               \
    unsigned short* lb = &ls[(hh) % 5][0];                           \
    gload16(srcA + (hh) * 32, lb + w * 512);                         \
    gload16(srcB1 + (hh) * 32, lb + 4096 + w * 512);                 \
    gload16(srcB2 + (hh) * 32, lb + 4096 + (w + 8) * 512);           \
  } while (0)
#define LDF2(st, hh)                                                 \
  do {                                                               \
    const unsigned short* lb = &ls[(hh) % 5][0];                     \
    _Pragma("unroll") for (int m = 0; m < 4; ++m) af[st][m] = *(const bf16x8*)(lb + roA[m]); \
    _Pragma("unroll") for (int n = 0; n < 4; ++n) bv[st][n] = *(const bf16x8*)(lb + roB[n]); \
  } while (0)
#define MM2(st)                                                      \
  do {                                                               \
    __builtin_amdgcn_s_setprio(1);                                   \
    _Pragma("unroll") for (int m = 0; m < 4; ++m)                    \
      _Pragma("unroll") for (int n = 0; n < 4; ++n)                  \
        acc[m][n] = __builtin_amdgcn_mfma_f32_16x16x32_bf16(af[st][m], bv[st][n], acc[m][n], 0, 0, 0); \
    __builtin_amdgcn_s_setprio(0);                                   \
  } while (0)

  STG2(0); STG2(1); STG2(2); STG2(3);
  WB(6);
  LDF2(0, 0);
#pragma unroll
  for (int i = 0; i < 24; ++i) {
    if (i + 4 < 24) STG2(i + 4);
    if (i + 1 < 24) LDF2((i + 1) & 1, i + 1);
    MM2(i & 1);
    if (i <= 19)      WB(6);
    else if (i == 20) WB(3);
    else if (i == 21) WB(0);
  }
#undef STG2
#undef LDF2
#undef MM2

#pragma unroll
  for (int m = 0; m < 4; ++m)
#pragma unroll
    for (int j = 0; j < 4; ++j) {
      int row = wm * 64 + m * 16 + fg * 4 + j;
      int grow = m0 + row;
      if (grow < cnt) {
        int tk = wsI[64 + e * T_TOK + grow];
        float rw = routw[(size_t)tk * NEXP + e];
        float* orow = out + (size_t)tk * H_DIM + n0 + wn * 64;
#pragma unroll
        for (int n = 0; n < 4; ++n)
          atomicAdd(orow + n * 16 + fr, acc[m][n][j] * rw);
      }
    }
}

extern "C" void kernel_launch(void* const* d_in, const int* in_sizes, int n_in,
                              void* d_out, int out_size, void* d_ws, size_t ws_size,
                              hipStream_t stream) {
  const float* x      = (const float*)d_in[0];
  const float* gate_w = (const float*)d_in[1];
  const float* up_w   = (const float*)d_in[2];
  const float* down_w = (const float*)d_in[3];
  const float* routw  = (const float*)d_in[4];
  float* out = (float*)d_out;
  int* wsI = (int*)d_ws;

  unsigned short* x_bf = (unsigned short*)((char*)d_ws + 131072);
  unsigned short* gbf  = (unsigned short*)((char*)d_ws + 4458560);
  unsigned short* ubf  = (unsigned short*)((char*)d_ws + 17434688);
  unsigned short* dbf  = (unsigned short*)((char*)d_ws + 30410816);
  unsigned short* h    = (unsigned short*)((char*)d_ws + 42993728);

  compact_k<<<8, 512, 0, stream>>>(routw, wsI);
  pre_k<<<5640, 256, 0, stream>>>(x, gate_w, up_w, down_w, x_bf, gbf, ubf, dbf, out);
  gemm1_k<<<768, 512, 0, stream>>>(x_bf, gbf, ubf, wsI, h);
  gemm2_k<<<512, 512, 0, stream>>>(h, dbf, wsI, routw, out);
}